// Round 15
// baseline (210.937 us; speedup 1.0000x reference)
//
#include <hip/hip_runtime.h>
#include <hip/hip_bf16.h>

// Problem dims (fixed)
// B=2, N=2048, D=1024, H=16, DK=64
// x: [2,2048,1024] f32; Wkqv: [16,1024,192] f32; bkqv: [16,192] f32;
// Wproj: [1024,1024] f32; bproj: [1024] f32; out: [2,2048,1024] f32

typedef __bf16 bf16x8 __attribute__((ext_vector_type(8)));
typedef float f32x4 __attribute__((ext_vector_type(4)));
typedef float f32x16 __attribute__((ext_vector_type(16)));

#define MFMA_BF16 __builtin_amdgcn_mfma_f32_16x16x32_bf16
#define MFMA32 __builtin_amdgcn_mfma_f32_32x32x16_bf16

static __device__ __forceinline__ unsigned cvtpk(float lo, float hi) {
    unsigned r;
    asm("v_cvt_pk_bf16_f32 %0, %1, %2" : "=v"(r) : "v"(lo), "v"(hi));
    return r;
}

// async global -> LDS, 16 B per lane; lds base must be wave-uniform
static __device__ __forceinline__ void gld16(const void* g, void* l) {
    __builtin_amdgcn_global_load_lds(
        (const __attribute__((address_space(1))) unsigned int*)g,
        (__attribute__((address_space(3))) unsigned int*)l, 16, 0, 0);
}

// ---------------- merged prep kernel ----------------
// blocks [0,4096):        x f32 -> xb bf16 (4 elems/thread)
// blocks [4096,7168):     Wkqv [16][1024][192] -> Wt [16][192][1024] bf16
// blocks [7168,8192):     Wproj [1024][1024] -> WpT [1024][1024] transposed bf16
__global__ __launch_bounds__(256) void prep(const float* __restrict__ x,
                                            const float* __restrict__ Wkqv,
                                            const float* __restrict__ Wproj,
                                            __hip_bfloat16* __restrict__ xb,
                                            __hip_bfloat16* __restrict__ Wt,
                                            __hip_bfloat16* __restrict__ WpT) {
    __shared__ float tile[32][33];
    const int bid = blockIdx.x, t = threadIdx.x;
    if (bid < 4096) {
        int i = (bid * 256 + t) * 4;
        float4 v = *(const float4*)&x[i];
        struct alignas(8) bh4 { __hip_bfloat16 a, b, c, d; };
        bh4 r{__float2bfloat16(v.x), __float2bfloat16(v.y),
              __float2bfloat16(v.z), __float2bfloat16(v.w)};
        *(bh4*)&xb[i] = r;
        return;
    }
    const int tx = t & 31, ty = t >> 5;  // (32,8)
    const float* in;
    __hip_bfloat16* out;
    int R, C, r0, c0;
    if (bid < 7168) {
        int r = bid - 4096;                   // (6,32,16) -> bx + 6*by + 192*bz
        int bz = r / 192, rem = r % 192, by = rem / 6, bx = rem % 6;
        R = 1024; C = 192;
        in = Wkqv + (size_t)bz * R * C;
        out = Wt + (size_t)bz * R * C;
        r0 = by * 32; c0 = bx * 32;
    } else {
        int r = bid - 7168;                   // (32,32)
        int by = r / 32, bx = r % 32;
        R = 1024; C = 1024;
        in = Wproj; out = WpT;
        r0 = by * 32; c0 = bx * 32;
    }
#pragma unroll
    for (int j = 0; j < 32; j += 8)
        tile[ty + j][tx] = in[(size_t)(r0 + ty + j) * C + (c0 + tx)];
    __syncthreads();
#pragma unroll
    for (int j = 0; j < 32; j += 8)
        out[(size_t)(c0 + ty + j) * R + (r0 + tx)] = __float2bfloat16(tile[tx][ty + j]);
}

// ---------------- QKV GEMM (256x192 tile = one head, fused repack) --------
// Per block: rows row0..row0+256 of x (bn), cols = head h's 192 outputs.
// Counted-vmcnt double-buffered K-loop (BK=64, 16 tiles), 8 waves (2x4),
// per-wave 128x48 output. Epilogue: acc(+bias, K*1/8) -> LDS [256][204]
// -> fragment-major Kf/Qf/Vf direct (repack fused; C never materialized).
__global__ __launch_bounds__(512) void gemm_qkv(const __hip_bfloat16* __restrict__ Ag,
                                                const __hip_bfloat16* __restrict__ Btg,
                                                const float* __restrict__ bias,
                                                __hip_bfloat16* __restrict__ Kf,
                                                __hip_bfloat16* __restrict__ Qf,
                                                __hip_bfloat16* __restrict__ Vf) {
    __shared__ __hip_bfloat16 smem[57344];  // dbuf: A 2x16384 | B 2x12288; reused by epilogue
    const int t = threadIdx.x;
    const int lane = t & 63, wid = t >> 6;  // 8 waves
    const int wm = wid >> 2, wn = wid & 3;  // 2 x 4
    const int h = blockIdx.x;               // head = N-tile (192 cols)
    const int row0 = blockIdx.y * 256;
    const int col0 = h * 192;
    const int lr = lane & 15, lg = lane >> 4;
    const int g_r = lane >> 3;                   // row within 8-row staging group
    const int g_s8 = ((lane & 7) ^ g_r) * 8;     // inverse-swizzled global slot
    const int sw0 = ((lg) ^ (lr & 7)) * 8;       // swizzled ds_read slot, kk=0..31
    const int sw1 = ((4 + lg) ^ (lr & 7)) * 8;   // kk=32..63

#define STAGE_QKV(buf, kt)                                                            \
    do {                                                                              \
        const int k0_ = (kt) * 64;                                                    \
        __hip_bfloat16* Ad_ = smem + (buf) * 16384;                                   \
        __hip_bfloat16* Bd_ = smem + 32768 + (buf) * 12288;                           \
        _Pragma("unroll") for (int r_ = 0; r_ < 4; ++r_) {                            \
            const int grp_ = r_ * 8 + wid;                                            \
            gld16(&Ag[(size_t)(row0 + grp_ * 8 + g_r) * 1024 + k0_ + g_s8],           \
                  Ad_ + grp_ * 512);                                                  \
        }                                                                             \
        _Pragma("unroll") for (int r_ = 0; r_ < 3; ++r_) {                            \
            const int grp_ = r_ * 8 + wid;                                            \
            gld16(&Btg[(size_t)(col0 + grp_ * 8 + g_r) * 1024 + k0_ + g_s8],          \
                  Bd_ + grp_ * 512);                                                  \
        }                                                                             \
    } while (0)

    f32x4 acc[8][3] = {};

    // prologue: stage tiles 0,1; wait for tile 0 only (7 loads/stage)
    STAGE_QKV(0, 0);
    STAGE_QKV(1, 1);
    asm volatile("s_waitcnt vmcnt(7)" ::: "memory");
    __builtin_amdgcn_sched_barrier(0);
    __builtin_amdgcn_s_barrier();
    __builtin_amdgcn_sched_barrier(0);

    int cur = 0;
    for (int kt = 0; kt < 16; ++kt) {
        const __hip_bfloat16* Ab = smem + cur * 16384;
        const __hip_bfloat16* Bb = smem + 32768 + cur * 12288;
        bf16x8 af[8], bf[3];
        // ---- kk = 0..31 ----
#pragma unroll
        for (int j = 0; j < 3; ++j)
            bf[j] = *(const bf16x8*)&Bb[(wn * 48 + j * 16 + lr) * 64 + sw0];
#pragma unroll
        for (int i = 0; i < 8; ++i)
            af[i] = *(const bf16x8*)&Ab[(wm * 128 + i * 16 + lr) * 64 + sw0];
        __builtin_amdgcn_s_setprio(1);
#pragma unroll
        for (int i = 0; i < 8; ++i)
#pragma unroll
            for (int j = 0; j < 3; ++j)
                acc[i][j] = MFMA_BF16(af[i], bf[j], acc[i][j], 0, 0, 0);
        __builtin_amdgcn_s_setprio(0);
        // ---- kk = 32..63 ----
#pragma unroll
        for (int j = 0; j < 3; ++j)
            bf[j] = *(const bf16x8*)&Bb[(wn * 48 + j * 16 + lr) * 64 + sw1];
#pragma unroll
        for (int i = 0; i < 8; ++i)
            af[i] = *(const bf16x8*)&Ab[(wm * 128 + i * 16 + lr) * 64 + sw1];
        asm volatile("s_waitcnt lgkmcnt(0)" ::: "memory");
        __builtin_amdgcn_sched_barrier(0);
        __builtin_amdgcn_s_barrier();
        __builtin_amdgcn_sched_barrier(0);
        // buffer cur free -> stage tile kt+2 into it (loads span barriers)
        if (kt + 2 < 16) STAGE_QKV(cur, kt + 2);
        __builtin_amdgcn_s_setprio(1);
#pragma unroll
        for (int i = 0; i < 8; ++i)
#pragma unroll
            for (int j = 0; j < 3; ++j)
                acc[i][j] = MFMA_BF16(af[i], bf[j], acc[i][j], 0, 0, 0);
        __builtin_amdgcn_s_setprio(0);
        if (kt <= 13) {
            asm volatile("s_waitcnt vmcnt(7)" ::: "memory");  // tile kt+1 ready, kt+2 in flight
        } else {
            asm volatile("s_waitcnt vmcnt(0)" ::: "memory");
        }
        __builtin_amdgcn_sched_barrier(0);
        __builtin_amdgcn_s_barrier();
        __builtin_amdgcn_sched_barrier(0);
        cur ^= 1;
    }
#undef STAGE_QKV

    // ---- fused epilogue: acc -> LDS [256][204] (bias + K-scale applied) ----
    const int b = row0 >> 11, n_base = row0 & 2047, bh = b * 16 + h;
    __hip_bfloat16 (*tile)[204] = (__hip_bfloat16 (*)[204])smem;
#pragma unroll
    for (int i = 0; i < 8; ++i)
#pragma unroll
        for (int j = 0; j < 3; ++j)
#pragma unroll
            for (int r = 0; r < 4; ++r) {
                int trow = wm * 128 + i * 16 + lg * 4 + r;
                int tcol = wn * 48 + j * 16 + lr;
                float v = acc[i][j][r] + bias[col0 + tcol];
                if (tcol % 3 == 0) v *= 0.125f;  // K pre-scale (1/sqrt(dk))
                tile[trow][tcol] = __float2bfloat16(v);
            }
    __syncthreads();
    // ---- fragment-major writes (identical mapping to validated repack) ----
#pragma unroll
    for (int k = 0; k < 4; ++k) {
        const int c = t + 512 * k;
        const int l = c & 63, lo = l & 31, hi = l >> 5;
        // K: chunks [so(8)][dc(4)][l(64)] ; elem = tile[so*32+lo][3*(dc*16+8*hi+i)]
        {
            const int dc = (c >> 6) & 3, so = c >> 8;
            ushort u[8];
#pragma unroll
            for (int i = 0; i < 8; ++i)
                u[i] = *(const ushort*)&tile[so * 32 + lo][3 * (dc * 16 + 8 * hi + i)];
            *(uint4*)&Kf[(((size_t)bh * 64 + (n_base >> 5) + so) * 4 + dc) * 512 + l * 8] =
                *(const uint4*)u;
        }
        // Q: chunks [mt_off(4)][sub(2)][dc(4)][l] ; elem = tile[mt_off*64+sub*32+lo][3*d+1]
        {
            const int dc = (c >> 6) & 3, sub = (c >> 8) & 1, mt_off = c >> 9;
            ushort u[8];
#pragma unroll
            for (int i = 0; i < 8; ++i)
                u[i] = *(const ushort*)&tile[mt_off * 64 + sub * 32 + lo]
                                           [3 * (dc * 16 + 8 * hi + i) + 1];
            *(uint4*)&Qf[((((size_t)bh * 32 + (n_base >> 6) + mt_off) * 2 + sub) * 4 + dc) * 512 +
                         l * 8] = *(const uint4*)u;
        }
        // V: chunks [mt_off(4)][kc(4)][accN(2)][l] ; elem = tile[mt_off*64+kc*16+8*hi+i][3*(accN*32+lo)+2]
        {
            const int accN = (c >> 6) & 1, kc = (c >> 7) & 3, mt_off = c >> 9;
            ushort u[8];
#pragma unroll
            for (int i = 0; i < 8; ++i)
                u[i] = *(const ushort*)&tile[mt_off * 64 + kc * 16 + 8 * hi + i]
                                           [3 * (accN * 32 + lo) + 2];
            *(uint4*)&Vf[((((size_t)bh * 32 + (n_base >> 6) + mt_off) * 4 + kc) * 2 + accN) * 512 +
                         l * 8] = *(const uint4*)u;
        }
    }
}

// ---------------- flash attention (swapped 32x32, 4-way m-split) ----------
// R12-proven decode + body, with two attn-local additions:
//  (a) two-phase TREE merge (mbuf[2] slots, 22KB LDS -> 6 blocks/CU vs 5)
//  (b) defer-rescale THR=0: skip the 64 acc*=scale v_muls when the running
//      max did not grow (__all(mx <= m_run)); scale==exp(0)==1 there, so the
//      skip is bit-exact. S stays zero-init; rescale path identical to R6
//      (R7/R8 spill trap avoided: acc never written in the skip path).
__global__ __launch_bounds__(256, 3) void attn_fwd(const __hip_bfloat16* __restrict__ Kf,
                                                   const __hip_bfloat16* __restrict__ Qf,
                                                   const __hip_bfloat16* __restrict__ Vf,
                                                   __hip_bfloat16* __restrict__ sa) {
    __shared__ float mbuf[2][64][35];
    __shared__ __hip_bfloat16 ot[32][66];
    const int id = blockIdx.x;
    const int xcd = id & 7, qq = id >> 3;
    const int bh = xcd * 4 + (qq & 3);
    const int slice = 63 - (qq >> 2);
    const int t = threadIdx.x, lane = t & 63, wid = t >> 6;
    const int col = lane & 31, half = lane >> 5;
    const int par = wid;
    const int n0 = slice * 32;

    const __hip_bfloat16* Kfp = Kf + (size_t)bh * 131072;
    const __hip_bfloat16* Qfp = Qf + (size_t)bh * 131072;
    const __hip_bfloat16* Vfp = Vf + (size_t)bh * 131072;

    bf16x8 kf[4];
#pragma unroll
    for (int dc = 0; dc < 4; ++dc)
        kf[dc] = *(const bf16x8*)&Kfp[((size_t)slice * 4 + dc) * 512 + lane * 8];

    f32x16 acc0 = {}, acc1 = {};
    float m_run = -3.0e29f, l_run = 0.f;
    const int ng = n0 + col;
    const int T = (n0 + 95) >> 6;

    bf16x8 qa[4], qb[4];
    if (par < T) {
#pragma unroll
        for (int dc = 0; dc < 4; ++dc) {
            qa[dc] = *(const bf16x8*)&Qfp[(((size_t)par * 2 + 0) * 4 + dc) * 512 + lane * 8];
            qb[dc] = *(const bf16x8*)&Qfp[(((size_t)par * 2 + 1) * 4 + dc) * 512 + lane * 8];
        }
    }

    for (int j = par; j < T; j += 4) {
        const int m0 = j << 6;
        bf16x8 va[4], vb[4];
#pragma unroll
        for (int kc = 0; kc < 4; ++kc) {
            va[kc] = *(const bf16x8*)&Vfp[(((size_t)j * 4 + kc) * 2 + 0) * 512 + lane * 8];
            vb[kc] = *(const bf16x8*)&Vfp[(((size_t)j * 4 + kc) * 2 + 1) * 512 + lane * 8];
        }
        f32x16 s0 = {}, s1 = {};
        __builtin_amdgcn_s_setprio(1);
#pragma unroll
        for (int dc = 0; dc < 4; ++dc) s0 = MFMA32(qa[dc], kf[dc], s0, 0, 0, 0);
#pragma unroll
        for (int dc = 0; dc < 4; ++dc) s1 = MFMA32(qb[dc], kf[dc], s1, 0, 0, 0);
        __builtin_amdgcn_s_setprio(0);
        if (j + 4 < T) {
#pragma unroll
            for (int dc = 0; dc < 4; ++dc) {
                qa[dc] = *(const bf16x8*)&Qfp[(((size_t)(j + 4) * 2 + 0) * 4 + dc) * 512 + lane * 8];
                qb[dc] = *(const bf16x8*)&Qfp[(((size_t)(j + 4) * 2 + 1) * 4 + dc) * 512 + lane * 8];
            }
        }
        if (m0 + 63 > n0) {
            const int mb = m0 + 4 * half;
#pragma unroll
            for (int r = 0; r < 16; ++r) {
                int mg = mb + (r & 3) + 8 * (r >> 2);
                if (mg > ng)      s0[r] = -1e30f;
                if (mg + 32 > ng) s1[r] = -1e30f;
            }
        }
        float mx = s0[0];
#pragma unroll
        for (int r = 1; r < 16; ++r) mx = fmaxf(mx, s0[r]);
#pragma unroll
        for (int r = 0; r < 16; ++r) mx = fmaxf(mx, s1[r]);
        mx = fmaxf(mx, __shfl_xor(mx, 32));
        float rs = 0.f;
        if (__all(mx <= m_run)) {
            // max did not grow anywhere in the wave: scale == 1, acc untouched
#pragma unroll
            for (int r = 0; r < 16; ++r) { s0[r] = __expf(s0[r] - m_run); rs += s0[r]; }
#pragma unroll
            for (int r = 0; r < 16; ++r) { s1[r] = __expf(s1[r] - m_run); rs += s1[r]; }
            rs += __shfl_xor(rs, 32);
            l_run += rs;
        } else {
            float nm = fmaxf(m_run, mx);
            float scale = __expf(m_run - nm);
            m_run = nm;
#pragma unroll
            for (int r = 0; r < 16; ++r) { s0[r] = __expf(s0[r] - nm); rs += s0[r]; }
#pragma unroll
            for (int r = 0; r < 16; ++r) { s1[r] = __expf(s1[r] - nm); rs += s1[r]; }
            rs += __shfl_xor(rs, 32);
            l_run = l_run * scale + rs;
            acc0 *= scale;
            acc1 *= scale;
        }

#pragma unroll
        for (int kc = 0; kc < 4; ++kc) {
            float p0, p1, p2, p3, p4, p5, p6, p7;
            if (kc == 0)      { p0=s0[0]; p1=s0[1]; p2=s0[2]; p3=s0[3]; p4=s0[4]; p5=s0[5]; p6=s0[6]; p7=s0[7]; }
            else if (kc == 1) { p0=s0[8]; p1=s0[9]; p2=s0[10]; p3=s0[11]; p4=s0[12]; p5=s0[13]; p6=s0[14]; p7=s0[15]; }
            else if (kc == 2) { p0=s1[0]; p1=s1[1]; p2=s1[2]; p3=s1[3]; p4=s1[4]; p5=s1[5]; p6=s1[6]; p7=s1[7]; }
            else              { p0=s1[8]; p1=s1[9]; p2=s1[10]; p3=s1[11]; p4=s1[12]; p5=s1[13]; p6=s1[14]; p7=s1[15]; }
            unsigned a0 = cvtpk(p0, p1), a1 = cvtpk(p2, p3);
            unsigned a2 = cvtpk(p4, p5), a3 = cvtpk(p6, p7);
            unsigned t0 = __shfl_xor(a0, 32), t1 = __shfl_xor(a1, 32);
            unsigned t2 = __shfl_xor(a2, 32), t3 = __shfl_xor(a3, 32);
            union { unsigned u[4]; bf16x8 v; } pb;
            pb.u[0] = half ? t2 : a0;
            pb.u[1] = half ? t3 : a1;
            pb.u[2] = half ? a2 : t0;
            pb.u[3] = half ? a3 : t1;
            __builtin_amdgcn_s_setprio(1);
            acc0 = MFMA32(va[kc], pb.v, acc0, 0, 0, 0);
            acc1 = MFMA32(vb[kc], pb.v, acc1, 0, 0, 0);
            __builtin_amdgcn_s_setprio(0);
        }
    }

    // ---- two-phase tree merge: (0<-2, 1<-3) in parallel, then 0<-1 ----
    if (wid >= 2) {
#pragma unroll
        for (int r = 0; r < 16; ++r) {
            mbuf[wid - 2][lane][r]      = acc0[r];
            mbuf[wid - 2][lane][16 + r] = acc1[r];
        }
        mbuf[wid - 2][lane][32] = m_run;
        mbuf[wid - 2][lane][33] = l_run;
    }
    __syncthreads();
    if (wid < 2) {
        float mB = mbuf[wid][lane][32], lB = mbuf[wid][lane][33];
        float nm = fmaxf(m_run, mB);
        float sA = __expf(m_run - nm), sB = __expf(mB - nm);
        m_run = nm;
        l_run = l_run * sA + lB * sB;
#pragma unroll
        for (int r = 0; r < 16; ++r) {
            acc0[r] = acc0[r] * sA + mbuf[wid][lane][r] * sB;
            acc1[r] = acc1[r] * sA + mbuf[wid][lane][16 + r] * sB;
        }
    }
    __syncthreads();
    if (wid == 1) {
#pragma unroll
        for (int r = 0; r < 16; ++r) {
            mbuf[0][lane][r]      = acc0[r];
            mbuf[0][lane][16 + r] = acc1[r];
        }
        mbuf[0][lane][32] = m_run;
        mbuf[0][lane][33] = l_run;
    }
    __syncthreads();
    if (!wid) {
        float mB = mbuf[0][lane][32], lB = mbuf[0][lane][33];
        float nm = fmaxf(m_run, mB);
        float sA = __expf(m_run - nm), sB = __expf(mB - nm);
        m_run = nm;
        l_run = l_run * sA + lB * sB;
#pragma unroll
        for (int r = 0; r < 16; ++r) {
            acc0[r] = acc0[r] * sA + mbuf[0][lane][r] * sB;
            acc1[r] = acc1[r] * sA + mbuf[0][lane][16 + r] * sB;
        }
        float inv = 1.0f / l_run;
#pragma unroll
        for (int r = 0; r < 16; ++r) {
            int d0 = (r & 3) + 8 * (r >> 2) + 4 * half;
            ot[col][d0]      = __float2bfloat16(acc0[r] * inv);
            ot[col][32 + d0] = __float2bfloat16(acc1[r] * inv);
        }
        const int b = bh >> 4, h = bh & 15;
#pragma unroll
        for (int tt = 0; tt < 16; ++tt) {
            int rrow = tt * 2 + half;
            unsigned v = *(const unsigned*)&ot[rrow][col * 2];
            *(unsigned*)&sa[((size_t)(b * 2048 + n0 + rrow)) * 1024 + h * 64 + col * 2] = v;
        }
    }
}

// ---------------- output projection (128x128, counted-vmcnt dbuf) --------
__global__ __launch_bounds__(256) void gemm_proj(const __hip_bfloat16* __restrict__ Ag,
                                                 const __hip_bfloat16* __restrict__ Btg,
                                                 const float* __restrict__ bias,
                                                 float* __restrict__ out) {
    __shared__ __hip_bfloat16 smem[32768];  // dbuf: A 2x8192 | B 2x8192
    const int t = threadIdx.x;
    const int lane = t & 63, wid = t >> 6;  // 4 waves
    const int wm = wid >> 1, wn = wid & 1;  // 2 x 2
    const int row0 = blockIdx.y * 128, col0 = blockIdx.x * 128;
    const int lr = lane & 15, lg = lane >> 4;
    const int g_r = lane >> 3;
    const int g_s8 = ((lane & 7) ^ g_r) * 8;
    const int sw0 = ((lg) ^ (lr & 7)) * 8;
    const int sw1 = ((4 + lg) ^ (lr & 7)) * 8;

#define STAGE_PROJ(buf, kt)                                                           \
    do {                                                                              \
        const int k0_ = (kt) * 64;                                                    \
        __hip_bfloat16* Ad_ = smem + (buf) * 8192;                                    \
        __hip_bfloat16* Bd_ = smem + 16384 + (buf) * 8192;                            \
        _Pragma("unroll") for (int r_ = 0; r_ < 4; ++r_) {                            \
            const int grp_ = r_ * 4 + wid;                                            \
            gld16(&Ag[(size_t)(row0 + grp_ * 8 + g_r) * 1024 + k0_ + g_s8],           \
                  Ad_ + grp_ * 512);                                                  \
            gld16(&Btg[(size_t)(col0 + grp_ * 8 + g_r) * 1024 + k0_ + g_s8],          \
                  Bd_ + grp_ * 512);                                                  \
        }                                                                             \
    } while (0)

    f32x4 acc[4][4] = {};

    STAGE_PROJ(0, 0);
    STAGE_PROJ(1, 1);
    asm volatile("s_waitcnt vmcnt(8)" ::: "memory");
    __builtin_amdgcn_sched_barrier(0);
    __builtin_amdgcn_s_barrier();
    __builtin_amdgcn_sched_barrier(0);

    int cur = 0;
    for (int kt = 0; kt < 16; ++kt) {
        const __hip_bfloat16* Ab = smem + cur * 8192;
        const __hip_bfloat16* Bb = smem + 16384 + cur * 8192;
        bf16x8 af[4], bf[4];
#pragma unroll
        for (int j = 0; j < 4; ++j)
            bf[j] = *(const bf16x8*)&Bb[(wn * 64 + j * 16 + lr) * 64 + sw0];
#pragma unroll
        for (int i = 0; i < 4; ++i)
            af[i] = *(const bf16x8*)&Ab[(wm * 64 + i * 16 + lr) * 64 + sw0];
        __builtin_amdgcn_s_setprio(1);
#pragma unroll
        for (int i = 0; i < 4; ++i)
#pragma unroll
            for (int j = 0; j < 4; ++j)
                acc[i][j] = MFMA_BF16(af[i], bf[j], acc[i][j], 0, 0, 0);
        __builtin_amdgcn_s_setprio(0);
#pragma unroll
        for (int j = 0; j < 4; ++j)
            bf[j] = *(const bf16x8*)&Bb[(wn * 64 + j * 16 + lr) * 64 + sw1];
#pragma unroll
        for (int i = 0; i < 4; ++i)
            af[i] = *(const bf16x8*)&Ab[(wm * 64 + i * 16 + lr) * 64 + sw1];
        asm volatile("s_waitcnt lgkmcnt(0)" ::: "memory");
        __builtin_amdgcn_sched_barrier(0);
        __builtin_amdgcn_s_barrier();
        __builtin_amdgcn_sched_barrier(0);
        if (kt + 2 < 16) STAGE_PROJ(cur, kt + 2);
        __builtin_amdgcn_s_setprio(1);
#pragma unroll
        for (int i = 0; i < 4; ++i)
#pragma unroll
            for (int j = 0; j < 4; ++j)
                acc[i][j] = MFMA_BF16(af[i], bf[j], acc[i][j], 0, 0, 0);
        __builtin_amdgcn_s_setprio(0);
        if (kt <= 13) {
            asm volatile("s_waitcnt vmcnt(8)" ::: "memory");
        } else {
            asm volatile("s_waitcnt vmcnt(0)" ::: "memory");
        }
        __builtin_amdgcn_sched_barrier(0);
        __builtin_amdgcn_s_barrier();
        __builtin_amdgcn_sched_barrier(0);
        cur ^= 1;
    }
#undef STAGE_PROJ

#pragma unroll
    for (int i = 0; i < 4; ++i)
#pragma unroll
        for (int j = 0; j < 4; ++j)
#pragma unroll
            for (int r = 0; r < 4; ++r) {
                int rg = row0 + wm * 64 + i * 16 + lg * 4 + r;
                int cg = col0 + wn * 64 + j * 16 + lr;
                out[(size_t)rg * 1024 + cg] = acc[i][j][r] + bias[cg];
            }
}

// ---------------- launch ----------------
extern "C" void kernel_launch(void* const* d_in, const int* in_sizes, int n_in,
                              void* d_out, int out_size, void* d_ws, size_t ws_size,
                              hipStream_t stream) {
    const float* x     = (const float*)d_in[0];  // [2,2048,1024]
    const float* Wkqv  = (const float*)d_in[1];  // [16,1024,192]
    const float* bkqv  = (const float*)d_in[2];  // [16,192] -> flat [3072]
    const float* Wproj = (const float*)d_in[3];  // [1024,1024]
    const float* bproj = (const float*)d_in[4];  // [1024]

    char* w = (char*)d_ws;
    // workspace layout (42 MB):
    // [0,8M):    xb (dead after gemm_qkv), then sab (attn output)
    // [8M,14M):  Wt
    // [16M,24M): Kf   [24M,32M): Qf   [32M,40M): Vf
    // [40M,42M): WpT
    __hip_bfloat16* xb  = (__hip_bfloat16*)(w + 0);
    __hip_bfloat16* sab = (__hip_bfloat16*)(w + 0);
    __hip_bfloat16* Wt  = (__hip_bfloat16*)(w + 8388608);
    __hip_bfloat16* Kf  = (__hip_bfloat16*)(w + 16777216);
    __hip_bfloat16* Qf  = (__hip_bfloat16*)(w + 25165824);
    __hip_bfloat16* Vf  = (__hip_bfloat16*)(w + 33554432);
    __hip_bfloat16* WpT = (__hip_bfloat16*)(w + 41943040);
    if (ws_size < 50331648) return;

    prep<<<8192, 256, 0, stream>>>(x, Wkqv, Wproj, xb, Wt, WpT);
    gemm_qkv<<<dim3(16, 16), 512, 0, stream>>>(xb, Wt, bkqv, Kf, Qf, Vf);
    attn_fwd<<<2048, 256, 0, stream>>>(Kf, Qf, Vf, sab);
    gemm_proj<<<dim3(8, 32), 256, 0, stream>>>(sab, WpT, bproj, (float*)d_out);
}

// Round 16
// 95.246 us; speedup vs baseline: 2.2147x; 2.2147x over previous
//
#include <hip/hip_runtime.h>
#include <hip/hip_bf16.h>

// Problem dims (fixed)
// B=2, N=2048, D=1024, H=16, DK=64
// x: [2,2048,1024] f32; Wkqv: [16,1024,192] f32; bkqv: [16,192] f32;
// Wproj: [1024,1024] f32; bproj: [1024] f32; out: [2,2048,1024] f32

typedef __bf16 bf16x8 __attribute__((ext_vector_type(8)));
typedef float f32x4 __attribute__((ext_vector_type(4)));
typedef float f32x16 __attribute__((ext_vector_type(16)));

#define MFMA_BF16 __builtin_amdgcn_mfma_f32_16x16x32_bf16
#define MFMA32 __builtin_amdgcn_mfma_f32_32x32x16_bf16

static __device__ __forceinline__ unsigned cvtpk(float lo, float hi) {
    unsigned r;
    asm("v_cvt_pk_bf16_f32 %0, %1, %2" : "=v"(r) : "v"(lo), "v"(hi));
    return r;
}

// async global -> LDS, 16 B per lane; lds base must be wave-uniform
static __device__ __forceinline__ void gld16(const void* g, void* l) {
    __builtin_amdgcn_global_load_lds(
        (const __attribute__((address_space(1))) unsigned int*)g,
        (__attribute__((address_space(3))) unsigned int*)l, 16, 0, 0);
}

// ---------------- merged prep kernel ----------------
// blocks [0,4096):        x f32 -> xb bf16 (4 elems/thread)
// blocks [4096,7168):     Wkqv [16][1024][192] -> Wt [16][192][1024] bf16
// blocks [7168,8192):     Wproj [1024][1024] -> WpT [1024][1024] transposed bf16
__global__ __launch_bounds__(256) void prep(const float* __restrict__ x,
                                            const float* __restrict__ Wkqv,
                                            const float* __restrict__ Wproj,
                                            __hip_bfloat16* __restrict__ xb,
                                            __hip_bfloat16* __restrict__ Wt,
                                            __hip_bfloat16* __restrict__ WpT) {
    __shared__ float tile[32][33];
    const int bid = blockIdx.x, t = threadIdx.x;
    if (bid < 4096) {
        int i = (bid * 256 + t) * 4;
        float4 v = *(const float4*)&x[i];
        struct alignas(8) bh4 { __hip_bfloat16 a, b, c, d; };
        bh4 r{__float2bfloat16(v.x), __float2bfloat16(v.y),
              __float2bfloat16(v.z), __float2bfloat16(v.w)};
        *(bh4*)&xb[i] = r;
        return;
    }
    const int tx = t & 31, ty = t >> 5;  // (32,8)
    const float* in;
    __hip_bfloat16* out;
    int R, C, r0, c0;
    if (bid < 7168) {
        int r = bid - 4096;                   // (6,32,16) -> bx + 6*by + 192*bz
        int bz = r / 192, rem = r % 192, by = rem / 6, bx = rem % 6;
        R = 1024; C = 192;
        in = Wkqv + (size_t)bz * R * C;
        out = Wt + (size_t)bz * R * C;
        r0 = by * 32; c0 = bx * 32;
    } else {
        int r = bid - 7168;                   // (32,32)
        int by = r / 32, bx = r % 32;
        R = 1024; C = 1024;
        in = Wproj; out = WpT;
        r0 = by * 32; c0 = bx * 32;
    }
#pragma unroll
    for (int j = 0; j < 32; j += 8)
        tile[ty + j][tx] = in[(size_t)(r0 + ty + j) * C + (c0 + tx)];
    __syncthreads();
#pragma unroll
    for (int j = 0; j < 32; j += 8)
        out[(size_t)(c0 + ty + j) * R + (r0 + tx)] = __float2bfloat16(tile[tx][ty + j]);
}

// ---------------- QKV GEMM (256x192 tile = one head, fused repack) --------
// Per block: rows row0..row0+256 of x (bn), cols = head h's 192 outputs.
// Counted-vmcnt double-buffered K-loop (BK=64, 16 tiles), 8 waves (2x4),
// per-wave 128x48 output. Epilogue: acc(+bias, K*1/8) -> LDS [256][204]
// -> fragment-major Kf/Qf/Vf direct (repack fused; C never materialized).
__global__ __launch_bounds__(512) void gemm_qkv(const __hip_bfloat16* __restrict__ Ag,
                                                const __hip_bfloat16* __restrict__ Btg,
                                                const float* __restrict__ bias,
                                                __hip_bfloat16* __restrict__ Kf,
                                                __hip_bfloat16* __restrict__ Qf,
                                                __hip_bfloat16* __restrict__ Vf) {
    __shared__ __hip_bfloat16 smem[57344];  // dbuf: A 2x16384 | B 2x12288; reused by epilogue
    const int t = threadIdx.x;
    const int lane = t & 63, wid = t >> 6;  // 8 waves
    const int wm = wid >> 2, wn = wid & 3;  // 2 x 4
    const int h = blockIdx.x;               // head = N-tile (192 cols)
    const int row0 = blockIdx.y * 256;
    const int col0 = h * 192;
    const int lr = lane & 15, lg = lane >> 4;
    const int g_r = lane >> 3;                   // row within 8-row staging group
    const int g_s8 = ((lane & 7) ^ g_r) * 8;     // inverse-swizzled global slot
    const int sw0 = ((lg) ^ (lr & 7)) * 8;       // swizzled ds_read slot, kk=0..31
    const int sw1 = ((4 + lg) ^ (lr & 7)) * 8;   // kk=32..63

#define STAGE_QKV(buf, kt)                                                            \
    do {                                                                              \
        const int k0_ = (kt) * 64;                                                    \
        __hip_bfloat16* Ad_ = smem + (buf) * 16384;                                   \
        __hip_bfloat16* Bd_ = smem + 32768 + (buf) * 12288;                           \
        _Pragma("unroll") for (int r_ = 0; r_ < 4; ++r_) {                            \
            const int grp_ = r_ * 8 + wid;                                            \
            gld16(&Ag[(size_t)(row0 + grp_ * 8 + g_r) * 1024 + k0_ + g_s8],           \
                  Ad_ + grp_ * 512);                                                  \
        }                                                                             \
        _Pragma("unroll") for (int r_ = 0; r_ < 3; ++r_) {                            \
            const int grp_ = r_ * 8 + wid;                                            \
            gld16(&Btg[(size_t)(col0 + grp_ * 8 + g_r) * 1024 + k0_ + g_s8],          \
                  Bd_ + grp_ * 512);                                                  \
        }                                                                             \
    } while (0)

    f32x4 acc[8][3] = {};

    // prologue: stage tiles 0,1; wait for tile 0 only (7 loads/stage)
    STAGE_QKV(0, 0);
    STAGE_QKV(1, 1);
    asm volatile("s_waitcnt vmcnt(7)" ::: "memory");
    __builtin_amdgcn_sched_barrier(0);
    __builtin_amdgcn_s_barrier();
    __builtin_amdgcn_sched_barrier(0);

    int cur = 0;
    for (int kt = 0; kt < 16; ++kt) {
        const __hip_bfloat16* Ab = smem + cur * 16384;
        const __hip_bfloat16* Bb = smem + 32768 + cur * 12288;
        bf16x8 af[8], bf[3];
        // ---- kk = 0..31 ----
#pragma unroll
        for (int j = 0; j < 3; ++j)
            bf[j] = *(const bf16x8*)&Bb[(wn * 48 + j * 16 + lr) * 64 + sw0];
#pragma unroll
        for (int i = 0; i < 8; ++i)
            af[i] = *(const bf16x8*)&Ab[(wm * 128 + i * 16 + lr) * 64 + sw0];
        __builtin_amdgcn_s_setprio(1);
#pragma unroll
        for (int i = 0; i < 8; ++i)
#pragma unroll
            for (int j = 0; j < 3; ++j)
                acc[i][j] = MFMA_BF16(af[i], bf[j], acc[i][j], 0, 0, 0);
        __builtin_amdgcn_s_setprio(0);
        // ---- kk = 32..63 ----
#pragma unroll
        for (int j = 0; j < 3; ++j)
            bf[j] = *(const bf16x8*)&Bb[(wn * 48 + j * 16 + lr) * 64 + sw1];
#pragma unroll
        for (int i = 0; i < 8; ++i)
            af[i] = *(const bf16x8*)&Ab[(wm * 128 + i * 16 + lr) * 64 + sw1];
        asm volatile("s_waitcnt lgkmcnt(0)" ::: "memory");
        __builtin_amdgcn_sched_barrier(0);
        __builtin_amdgcn_s_barrier();
        __builtin_amdgcn_sched_barrier(0);
        // buffer cur free -> stage tile kt+2 into it (loads span barriers)
        if (kt + 2 < 16) STAGE_QKV(cur, kt + 2);
        __builtin_amdgcn_s_setprio(1);
#pragma unroll
        for (int i = 0; i < 8; ++i)
#pragma unroll
            for (int j = 0; j < 3; ++j)
                acc[i][j] = MFMA_BF16(af[i], bf[j], acc[i][j], 0, 0, 0);
        __builtin_amdgcn_s_setprio(0);
        if (kt <= 13) {
            asm volatile("s_waitcnt vmcnt(7)" ::: "memory");  // tile kt+1 ready, kt+2 in flight
        } else {
            asm volatile("s_waitcnt vmcnt(0)" ::: "memory");
        }
        __builtin_amdgcn_sched_barrier(0);
        __builtin_amdgcn_s_barrier();
        __builtin_amdgcn_sched_barrier(0);
        cur ^= 1;
    }
#undef STAGE_QKV

    // ---- fused epilogue: acc -> LDS [256][204] (bias + K-scale applied) ----
    const int b = row0 >> 11, n_base = row0 & 2047, bh = b * 16 + h;
    __hip_bfloat16 (*tile)[204] = (__hip_bfloat16 (*)[204])smem;
#pragma unroll
    for (int i = 0; i < 8; ++i)
#pragma unroll
        for (int j = 0; j < 3; ++j)
#pragma unroll
            for (int r = 0; r < 4; ++r) {
                int trow = wm * 128 + i * 16 + lg * 4 + r;
                int tcol = wn * 48 + j * 16 + lr;
                float v = acc[i][j][r] + bias[col0 + tcol];
                if (tcol % 3 == 0) v *= 0.125f;  // K pre-scale (1/sqrt(dk))
                tile[trow][tcol] = __float2bfloat16(v);
            }
    __syncthreads();
    // ---- fragment-major writes (identical mapping to validated repack) ----
#pragma unroll
    for (int k = 0; k < 4; ++k) {
        const int c = t + 512 * k;
        const int l = c & 63, lo = l & 31, hi = l >> 5;
        // K: chunks [so(8)][dc(4)][l(64)] ; elem = tile[so*32+lo][3*(dc*16+8*hi+i)]
        {
            const int dc = (c >> 6) & 3, so = c >> 8;
            ushort u[8];
#pragma unroll
            for (int i = 0; i < 8; ++i)
                u[i] = *(const ushort*)&tile[so * 32 + lo][3 * (dc * 16 + 8 * hi + i)];
            *(uint4*)&Kf[(((size_t)bh * 64 + (n_base >> 5) + so) * 4 + dc) * 512 + l * 8] =
                *(const uint4*)u;
        }
        // Q: chunks [mt_off(4)][sub(2)][dc(4)][l] ; elem = tile[mt_off*64+sub*32+lo][3*d+1]
        {
            const int dc = (c >> 6) & 3, sub = (c >> 8) & 1, mt_off = c >> 9;
            ushort u[8];
#pragma unroll
            for (int i = 0; i < 8; ++i)
                u[i] = *(const ushort*)&tile[mt_off * 64 + sub * 32 + lo]
                                           [3 * (dc * 16 + 8 * hi + i) + 1];
            *(uint4*)&Qf[((((size_t)bh * 32 + (n_base >> 6) + mt_off) * 2 + sub) * 4 + dc) * 512 +
                         l * 8] = *(const uint4*)u;
        }
        // V: chunks [mt_off(4)][kc(4)][accN(2)][l] ; elem = tile[mt_off*64+kc*16+8*hi+i][3*(accN*32+lo)+2]
        {
            const int accN = (c >> 6) & 1, kc = (c >> 7) & 3, mt_off = c >> 9;
            ushort u[8];
#pragma unroll
            for (int i = 0; i < 8; ++i)
                u[i] = *(const ushort*)&tile[mt_off * 64 + kc * 16 + 8 * hi + i]
                                           [3 * (accN * 32 + lo) + 2];
            *(uint4*)&Vf[((((size_t)bh * 32 + (n_base >> 6) + mt_off) * 4 + kc) * 2 + accN) * 512 +
                         l * 8] = *(const uint4*)u;
        }
    }
}

// ---------------- flash attention (swapped 32x32, 4-way m-split) ----------
// In-loop body: EXACT R12-proven straight-line softmax (no branches -- every
// branched variant spilled accumulators to scratch: R7/R8/R14, 4-6x cost).
// Post-loop: two-phase TREE merge only (mbuf[2] slots, 22.5KB LDS -> 6
// blocks/CU vs 5; merge depth 3->2). Post-loop acc branches are proven safe.
__global__ __launch_bounds__(256, 3) void attn_fwd(const __hip_bfloat16* __restrict__ Kf,
                                                   const __hip_bfloat16* __restrict__ Qf,
                                                   const __hip_bfloat16* __restrict__ Vf,
                                                   __hip_bfloat16* __restrict__ sa) {
    __shared__ float mbuf[2][64][35];
    __shared__ __hip_bfloat16 ot[32][66];
    const int id = blockIdx.x;
    const int xcd = id & 7, qq = id >> 3;
    const int bh = xcd * 4 + (qq & 3);
    const int slice = 63 - (qq >> 2);
    const int t = threadIdx.x, lane = t & 63, wid = t >> 6;
    const int col = lane & 31, half = lane >> 5;
    const int par = wid;
    const int n0 = slice * 32;

    const __hip_bfloat16* Kfp = Kf + (size_t)bh * 131072;
    const __hip_bfloat16* Qfp = Qf + (size_t)bh * 131072;
    const __hip_bfloat16* Vfp = Vf + (size_t)bh * 131072;

    bf16x8 kf[4];
#pragma unroll
    for (int dc = 0; dc < 4; ++dc)
        kf[dc] = *(const bf16x8*)&Kfp[((size_t)slice * 4 + dc) * 512 + lane * 8];

    f32x16 acc0 = {}, acc1 = {};
    float m_run = -3.0e29f, l_run = 0.f;
    const int ng = n0 + col;
    const int T = (n0 + 95) >> 6;

    bf16x8 qa[4], qb[4];
    if (par < T) {
#pragma unroll
        for (int dc = 0; dc < 4; ++dc) {
            qa[dc] = *(const bf16x8*)&Qfp[(((size_t)par * 2 + 0) * 4 + dc) * 512 + lane * 8];
            qb[dc] = *(const bf16x8*)&Qfp[(((size_t)par * 2 + 1) * 4 + dc) * 512 + lane * 8];
        }
    }

    for (int j = par; j < T; j += 4) {
        const int m0 = j << 6;
        bf16x8 va[4], vb[4];
#pragma unroll
        for (int kc = 0; kc < 4; ++kc) {
            va[kc] = *(const bf16x8*)&Vfp[(((size_t)j * 4 + kc) * 2 + 0) * 512 + lane * 8];
            vb[kc] = *(const bf16x8*)&Vfp[(((size_t)j * 4 + kc) * 2 + 1) * 512 + lane * 8];
        }
        f32x16 s0 = {}, s1 = {};
        __builtin_amdgcn_s_setprio(1);
#pragma unroll
        for (int dc = 0; dc < 4; ++dc) s0 = MFMA32(qa[dc], kf[dc], s0, 0, 0, 0);
#pragma unroll
        for (int dc = 0; dc < 4; ++dc) s1 = MFMA32(qb[dc], kf[dc], s1, 0, 0, 0);
        __builtin_amdgcn_s_setprio(0);
        if (j + 4 < T) {
#pragma unroll
            for (int dc = 0; dc < 4; ++dc) {
                qa[dc] = *(const bf16x8*)&Qfp[(((size_t)(j + 4) * 2 + 0) * 4 + dc) * 512 + lane * 8];
                qb[dc] = *(const bf16x8*)&Qfp[(((size_t)(j + 4) * 2 + 1) * 4 + dc) * 512 + lane * 8];
            }
        }
        if (m0 + 63 > n0) {
            const int mb = m0 + 4 * half;
#pragma unroll
            for (int r = 0; r < 16; ++r) {
                int mg = mb + (r & 3) + 8 * (r >> 2);
                if (mg > ng)      s0[r] = -1e30f;
                if (mg + 32 > ng) s1[r] = -1e30f;
            }
        }
        float mx = s0[0];
#pragma unroll
        for (int r = 1; r < 16; ++r) mx = fmaxf(mx, s0[r]);
#pragma unroll
        for (int r = 0; r < 16; ++r) mx = fmaxf(mx, s1[r]);
        mx = fmaxf(mx, __shfl_xor(mx, 32));
        float nm = fmaxf(m_run, mx);
        float scale = __expf(m_run - nm);
        m_run = nm;
        float rs = 0.f;
#pragma unroll
        for (int r = 0; r < 16; ++r) { s0[r] = __expf(s0[r] - nm); rs += s0[r]; }
#pragma unroll
        for (int r = 0; r < 16; ++r) { s1[r] = __expf(s1[r] - nm); rs += s1[r]; }
        rs += __shfl_xor(rs, 32);
        l_run = l_run * scale + rs;
        acc0 *= scale;
        acc1 *= scale;

#pragma unroll
        for (int kc = 0; kc < 4; ++kc) {
            float p0, p1, p2, p3, p4, p5, p6, p7;
            if (kc == 0)      { p0=s0[0]; p1=s0[1]; p2=s0[2]; p3=s0[3]; p4=s0[4]; p5=s0[5]; p6=s0[6]; p7=s0[7]; }
            else if (kc == 1) { p0=s0[8]; p1=s0[9]; p2=s0[10]; p3=s0[11]; p4=s0[12]; p5=s0[13]; p6=s0[14]; p7=s0[15]; }
            else if (kc == 2) { p0=s1[0]; p1=s1[1]; p2=s1[2]; p3=s1[3]; p4=s1[4]; p5=s1[5]; p6=s1[6]; p7=s1[7]; }
            else              { p0=s1[8]; p1=s1[9]; p2=s1[10]; p3=s1[11]; p4=s1[12]; p5=s1[13]; p6=s1[14]; p7=s1[15]; }
            unsigned a0 = cvtpk(p0, p1), a1 = cvtpk(p2, p3);
            unsigned a2 = cvtpk(p4, p5), a3 = cvtpk(p6, p7);
            unsigned t0 = __shfl_xor(a0, 32), t1 = __shfl_xor(a1, 32);
            unsigned t2 = __shfl_xor(a2, 32), t3 = __shfl_xor(a3, 32);
            union { unsigned u[4]; bf16x8 v; } pb;
            pb.u[0] = half ? t2 : a0;
            pb.u[1] = half ? t3 : a1;
            pb.u[2] = half ? a2 : t0;
            pb.u[3] = half ? a3 : t1;
            __builtin_amdgcn_s_setprio(1);
            acc0 = MFMA32(va[kc], pb.v, acc0, 0, 0, 0);
            acc1 = MFMA32(vb[kc], pb.v, acc1, 0, 0, 0);
            __builtin_amdgcn_s_setprio(0);
        }
    }

    // ---- two-phase tree merge: (0<-2, 1<-3) in parallel, then 0<-1 ----
    if (wid >= 2) {
#pragma unroll
        for (int r = 0; r < 16; ++r) {
            mbuf[wid - 2][lane][r]      = acc0[r];
            mbuf[wid - 2][lane][16 + r] = acc1[r];
        }
        mbuf[wid - 2][lane][32] = m_run;
        mbuf[wid - 2][lane][33] = l_run;
    }
    __syncthreads();
    if (wid < 2) {
        float mB = mbuf[wid][lane][32], lB = mbuf[wid][lane][33];
        float nm = fmaxf(m_run, mB);
        float sA = __expf(m_run - nm), sB = __expf(mB - nm);
        m_run = nm;
        l_run = l_run * sA + lB * sB;
#pragma unroll
        for (int r = 0; r < 16; ++r) {
            acc0[r] = acc0[r] * sA + mbuf[wid][lane][r] * sB;
            acc1[r] = acc1[r] * sA + mbuf[wid][lane][16 + r] * sB;
        }
    }
    __syncthreads();
    if (wid == 1) {
#pragma unroll
        for (int r = 0; r < 16; ++r) {
            mbuf[0][lane][r]      = acc0[r];
            mbuf[0][lane][16 + r] = acc1[r];
        }
        mbuf[0][lane][32] = m_run;
        mbuf[0][lane][33] = l_run;
    }
    __syncthreads();
    if (!wid) {
        float mB = mbuf[0][lane][32], lB = mbuf[0][lane][33];
        float nm = fmaxf(m_run, mB);
        float sA = __expf(m_run - nm), sB = __expf(mB - nm);
        m_run = nm;
        l_run = l_run * sA + lB * sB;
#pragma unroll
        for (int r = 0; r < 16; ++r) {
            acc0[r] = acc0[r] * sA + mbuf[0][lane][r] * sB;
            acc1[r] = acc1[r] * sA + mbuf[0][lane][16 + r] * sB;
        }
        float inv = 1.0f / l_run;
#pragma unroll
        for (int r = 0; r < 16; ++r) {
            int d0 = (r & 3) + 8 * (r >> 2) + 4 * half;
            ot[col][d0]      = __float2bfloat16(acc0[r] * inv);
            ot[col][32 + d0] = __float2bfloat16(acc1[r] * inv);
        }
        const int b = bh >> 4, h = bh & 15;
#pragma unroll
        for (int tt = 0; tt < 16; ++tt) {
            int rrow = tt * 2 + half;
            unsigned v = *(const unsigned*)&ot[rrow][col * 2];
            *(unsigned*)&sa[((size_t)(b * 2048 + n0 + rrow)) * 1024 + h * 64 + col * 2] = v;
        }
    }
}

// ---------------- output projection (128x128, counted-vmcnt dbuf) --------
__global__ __launch_bounds__(256) void gemm_proj(const __hip_bfloat16* __restrict__ Ag,
                                                 const __hip_bfloat16* __restrict__ Btg,
                                                 const float* __restrict__ bias,
                                                 float* __restrict__ out) {
    __shared__ __hip_bfloat16 smem[32768];  // dbuf: A 2x8192 | B 2x8192
    const int t = threadIdx.x;
    const int lane = t & 63, wid = t >> 6;  // 4 waves
    const int wm = wid >> 1, wn = wid & 1;  // 2 x 2
    const int row0 = blockIdx.y * 128, col0 = blockIdx.x * 128;
    const int lr = lane & 15, lg = lane >> 4;
    const int g_r = lane >> 3;
    const int g_s8 = ((lane & 7) ^ g_r) * 8;
    const int sw0 = ((lg) ^ (lr & 7)) * 8;
    const int sw1 = ((4 + lg) ^ (lr & 7)) * 8;

#define STAGE_PROJ(buf, kt)                                                           \
    do {                                                                              \
        const int k0_ = (kt) * 64;                                                    \
        __hip_bfloat16* Ad_ = smem + (buf) * 8192;                                    \
        __hip_bfloat16* Bd_ = smem + 16384 + (buf) * 8192;                            \
        _Pragma("unroll") for (int r_ = 0; r_ < 4; ++r_) {                            \
            const int grp_ = r_ * 4 + wid;                                            \
            gld16(&Ag[(size_t)(row0 + grp_ * 8 + g_r) * 1024 + k0_ + g_s8],           \
                  Ad_ + grp_ * 512);                                                  \
            gld16(&Btg[(size_t)(col0 + grp_ * 8 + g_r) * 1024 + k0_ + g_s8],          \
                  Bd_ + grp_ * 512);                                                  \
        }                                                                             \
    } while (0)

    f32x4 acc[4][4] = {};

    STAGE_PROJ(0, 0);
    STAGE_PROJ(1, 1);
    asm volatile("s_waitcnt vmcnt(8)" ::: "memory");
    __builtin_amdgcn_sched_barrier(0);
    __builtin_amdgcn_s_barrier();
    __builtin_amdgcn_sched_barrier(0);

    int cur = 0;
    for (int kt = 0; kt < 16; ++kt) {
        const __hip_bfloat16* Ab = smem + cur * 8192;
        const __hip_bfloat16* Bb = smem + 16384 + cur * 8192;
        bf16x8 af[4], bf[4];
#pragma unroll
        for (int j = 0; j < 4; ++j)
            bf[j] = *(const bf16x8*)&Bb[(wn * 64 + j * 16 + lr) * 64 + sw0];
#pragma unroll
        for (int i = 0; i < 4; ++i)
            af[i] = *(const bf16x8*)&Ab[(wm * 64 + i * 16 + lr) * 64 + sw0];
        __builtin_amdgcn_s_setprio(1);
#pragma unroll
        for (int i = 0; i < 4; ++i)
#pragma unroll
            for (int j = 0; j < 4; ++j)
                acc[i][j] = MFMA_BF16(af[i], bf[j], acc[i][j], 0, 0, 0);
        __builtin_amdgcn_s_setprio(0);
#pragma unroll
        for (int j = 0; j < 4; ++j)
            bf[j] = *(const bf16x8*)&Bb[(wn * 64 + j * 16 + lr) * 64 + sw1];
#pragma unroll
        for (int i = 0; i < 4; ++i)
            af[i] = *(const bf16x8*)&Ab[(wm * 64 + i * 16 + lr) * 64 + sw1];
        asm volatile("s_waitcnt lgkmcnt(0)" ::: "memory");
        __builtin_amdgcn_sched_barrier(0);
        __builtin_amdgcn_s_barrier();
        __builtin_amdgcn_sched_barrier(0);
        if (kt + 2 < 16) STAGE_PROJ(cur, kt + 2);
        __builtin_amdgcn_s_setprio(1);
#pragma unroll
        for (int i = 0; i < 4; ++i)
#pragma unroll
            for (int j = 0; j < 4; ++j)
                acc[i][j] = MFMA_BF16(af[i], bf[j], acc[i][j], 0, 0, 0);
        __builtin_amdgcn_s_setprio(0);
        if (kt <= 13) {
            asm volatile("s_waitcnt vmcnt(8)" ::: "memory");
        } else {
            asm volatile("s_waitcnt vmcnt(0)" ::: "memory");
        }
        __builtin_amdgcn_sched_barrier(0);
        __builtin_amdgcn_s_barrier();
        __builtin_amdgcn_sched_barrier(0);
        cur ^= 1;
    }
#undef STAGE_PROJ

#pragma unroll
    for (int i = 0; i < 4; ++i)
#pragma unroll
        for (int j = 0; j < 4; ++j)
#pragma unroll
            for (int r = 0; r < 4; ++r) {
                int rg = row0 + wm * 64 + i * 16 + lg * 4 + r;
                int cg = col0 + wn * 64 + j * 16 + lr;
                out[(size_t)rg * 1024 + cg] = acc[i][j][r] + bias[cg];
            }
}

// ---------------- launch ----------------
extern "C" void kernel_launch(void* const* d_in, const int* in_sizes, int n_in,
                              void* d_out, int out_size, void* d_ws, size_t ws_size,
                              hipStream_t stream) {
    const float* x     = (const float*)d_in[0];  // [2,2048,1024]
    const float* Wkqv  = (const float*)d_in[1];  // [16,1024,192]
    const float* bkqv  = (const float*)d_in[2];  // [16,192] -> flat [3072]
    const float* Wproj = (const float*)d_in[3];  // [1024,1024]
    const float* bproj = (const float*)d_in[4];  // [1024]

    char* w = (char*)d_ws;
    // workspace layout (42 MB):
    // [0,8M):    xb (dead after gemm_qkv), then sab (attn output)
    // [8M,14M):  Wt
    // [16M,24M): Kf   [24M,32M): Qf   [32M,40M): Vf
    // [40M,42M): WpT
    __hip_bfloat16* xb  = (__hip_bfloat16*)(w + 0);
    __hip_bfloat16* sab = (__hip_bfloat16*)(w + 0);
    __hip_bfloat16* Wt  = (__hip_bfloat16*)(w + 8388608);
    __hip_bfloat16* Kf  = (__hip_bfloat16*)(w + 16777216);
    __hip_bfloat16* Qf  = (__hip_bfloat16*)(w + 25165824);
    __hip_bfloat16* Vf  = (__hip_bfloat16*)(w + 33554432);
    __hip_bfloat16* WpT = (__hip_bfloat16*)(w + 41943040);
    if (ws_size < 50331648) return;

    prep<<<8192, 256, 0, stream>>>(x, Wkqv, Wproj, xb, Wt, WpT);
    gemm_qkv<<<dim3(16, 16), 512, 0, stream>>>(xb, Wt, bkqv, Kf, Qf, Vf);
    attn_fwd<<<2048, 256, 0, stream>>>(Kf, Qf, Vf, sab);
    gemm_proj<<<dim3(8, 32), 256, 0, stream>>>(sab, WpT, bproj, (float*)d_out);
}